// Round 9
// baseline (429.910 us; speedup 1.0000x reference)
//
#include <hip/hip_runtime.h>
#include <math.h>

#define DIN 128
#define HD 64
#define NEG 0.2f
#define BK 32

__device__ __forceinline__ float sigmoidf_(float x) { return 1.f / (1.f + __expf(-x)); }
__device__ __forceinline__ float tanhf_(float x)    { return 2.f / (1.f + __expf(-2.f*x)) - 1.f; }

// ---------------- CSR build ----------------
__global__ void k_count(const int* __restrict__ dst, int E, int* __restrict__ deg) {
  int e = blockIdx.x*256 + threadIdx.x;
  if (e < E) atomicAdd(&deg[dst[e]], 1);
}

__global__ void k_scan1(const int* __restrict__ deg, int n, int* __restrict__ rowst, int* __restrict__ bsum) {
  __shared__ int s[256];
  int i = blockIdx.x*256 + threadIdx.x;
  int v = (i < n) ? deg[i] : 0;
  s[threadIdx.x] = v;
  __syncthreads();
  for (int off = 1; off < 256; off <<= 1) {
    int t = (threadIdx.x >= off) ? s[threadIdx.x - off] : 0;
    __syncthreads();
    s[threadIdx.x] += t;
    __syncthreads();
  }
  if (i < n) rowst[i] = s[threadIdx.x] - v;
  if (threadIdx.x == 255) bsum[blockIdx.x] = s[255];
}

__global__ void k_scan2(int* bsum, int nb) {
  __shared__ int s[256];
  int v = (threadIdx.x < nb) ? bsum[threadIdx.x] : 0;
  s[threadIdx.x] = v;
  __syncthreads();
  for (int off = 1; off < 256; off <<= 1) {
    int t = (threadIdx.x >= off) ? s[threadIdx.x - off] : 0;
    __syncthreads();
    s[threadIdx.x] += t;
    __syncthreads();
  }
  if (threadIdx.x < nb) bsum[threadIdx.x] = s[threadIdx.x] - v;
}

__global__ void k_scan3(int* __restrict__ rowst, const int* __restrict__ bsum, int n, int E, int* __restrict__ deg) {
  int i = blockIdx.x*256 + threadIdx.x;
  if (i < n) { rowst[i] += bsum[blockIdx.x]; deg[i] = 0; }
  if (i == 0) rowst[n] = E;
}

__global__ void k_scatter(const int* __restrict__ src, const int* __restrict__ dst, int E,
                          const int* __restrict__ rowst, int* __restrict__ fill, int* __restrict__ csr) {
  int e = blockIdx.x*256 + threadIdx.x;
  if (e < E) {
    int d = dst[e];
    int pos = rowst[d] + atomicAdd(&fill[d], 1);
    csr[pos] = src[e];
  }
}

// ---------------- GRU weight re-layout ----------------
// B[k][c], k in [0,128): k<64 -> m-row (Wi), k>=64 -> h-row (Wh).
// c = j*4 + gate; gate 0: r-sum, 1: z-sum, 2: gi_n (Wi only), 3: gh_n (Wh only)
__global__ void k_wt2(const float* __restrict__ Wi, const float* __restrict__ Wh,
                      const float* __restrict__ bi, const float* __restrict__ bh,
                      float* __restrict__ B, float* __restrict__ bc) {
  int i = blockIdx.x*256 + threadIdx.x;
  if (i < 128*256) {
    int k = i >> 8, c = i & 255;
    int j = c >> 2, g = c & 3;
    float v;
    if (g == 0)      v = (k < 64) ? Wi[k*(3*HD) + j]        : Wh[(k-64)*(3*HD) + j];
    else if (g == 1) v = (k < 64) ? Wi[k*(3*HD) + HD + j]   : Wh[(k-64)*(3*HD) + HD + j];
    else if (g == 2) v = (k < 64) ? Wi[k*(3*HD) + 2*HD + j] : 0.f;
    else             v = (k < 64) ? 0.f                     : Wh[(k-64)*(3*HD) + 2*HD + j];
    B[i] = v;
  }
  if (i < 256) {
    int j = i >> 2, g = i & 3;
    float v;
    if (g == 0)      v = bi[j] + bh[j];
    else if (g == 1) v = bi[HD + j] + bh[HD + j];
    else if (g == 2) v = bi[2*HD + j];
    else             v = bh[2*HD + j];
    bc[i] = v;
  }
}

// ---------------- input projection as register-blocked GEMM (M=32 tile) ----------------
__global__ void __launch_bounds__(256) k_proj2(const float* __restrict__ x, const float* __restrict__ Win,
                       const float* __restrict__ bin, const float* __restrict__ aatt, int n,
                       float* __restrict__ h, float* __restrict__ ssrc, float* __restrict__ sdst) {
  __shared__ float A[DIN][32];   // 16KB
  int m_base = blockIdx.x * 32;
  int tx = threadIdx.x;
  {
    int m = tx & 31;
    int kq8 = tx >> 5;           // 0..7
    int node = m_base + m;
    bool valid = node < n;
    const float4* x4 = (const float4*)(x + (size_t)node*DIN);
#pragma unroll
    for (int it = 0; it < 4; ++it) {
      int kq = kq8*4 + it;       // 0..31
      int k0 = kq*4;
      float4 v = make_float4(0.f,0.f,0.f,0.f);
      if (valid) v = x4[kq];
      A[k0+0][m] = v.x; A[k0+1][m] = v.y; A[k0+2][m] = v.z; A[k0+3][m] = v.w;
    }
  }
  __syncthreads();

  int c_idx = tx & 31;           // 2 cols each
  int m_idx = tx >> 5;           // 8 node groups of 4
  int c0 = c_idx * 2;
  int m0 = m_idx * 4;

  float acc[4][2];
#pragma unroll
  for (int a = 0; a < 4; ++a) { acc[a][0] = 0.f; acc[a][1] = 0.f; }

#pragma unroll 4
  for (int k = 0; k < DIN; ++k) {
    float2 b = *(const float2*)(Win + k*HD + c0);
    float4 a0 = *(const float4*)(&A[k][m0]);
    float av[4] = {a0.x,a0.y,a0.z,a0.w};
#pragma unroll
    for (int a = 0; a < 4; ++a) { acc[a][0] += av[a]*b.x; acc[a][1] += av[a]*b.y; }
  }

  float b0 = bin[c0], b1 = bin[c0+1];
  float a_s0 = aatt[c0],    a_s1 = aatt[c0+1];
  float a_d0 = aatt[HD+c0], a_d1 = aatt[HD+c0+1];

#pragma unroll
  for (int a = 0; a < 4; ++a) {
    int node = m_base + m0 + a;
    float v0 = fmaxf(acc[a][0] + b0, 0.f);
    float v1 = fmaxf(acc[a][1] + b1, 0.f);
    if (node < n) {
      h[(size_t)node*HD + c0]   = v0;
      h[(size_t)node*HD + c0+1] = v1;
    }
    float ps = v0*a_s0 + v1*a_s1;
    float pd = v0*a_d0 + v1*a_d1;
#pragma unroll
    for (int off = 16; off; off >>= 1) { ps += __shfl_xor(ps, off); pd += __shfl_xor(pd, off); }
    if (c_idx == 0 && node < n) { ssrc[node] = ps; sdst[node] = pd; }
  }
}

// ---------------- fused score + softmax + gather: 16 lanes per node ----------------
__global__ void __launch_bounds__(256) k_sagg(const float* __restrict__ h, const float* __restrict__ ssrc,
                       const float* __restrict__ sdst, const int* __restrict__ rowst,
                       const int* __restrict__ csr, int n, float* __restrict__ mout) {
  int g16 = threadIdx.x >> 4;
  int l16 = threadIdx.x & 15;
  int node = blockIdx.x*16 + g16;
  if (node >= n) return;
  int s0 = rowst[node], s1 = rowst[node+1];
  int deg = s1 - s0;
  float4 acc = make_float4(0.f,0.f,0.f,0.f);
  if (deg <= 0) {
    *((float4*)(mout + (size_t)node*HD) + l16) = acc;
    return;
  }
  float sdv = sdst[node];

  if (deg <= 64) {
    float areg[4];
    int   ureg[4];
    float mx = -INFINITY;
#pragma unroll
    for (int c = 0; c < 4; ++c) {
      int idx = s0 + c*16 + l16;
      int uu = csr[(idx < s1) ? idx : s0];    // clamped safe read
      ureg[c] = uu;
      float sc = -INFINITY;
      if (idx < s1) {
        sc = ssrc[uu] + sdv;
        sc = (sc > 0.f) ? sc : NEG*sc;
      }
      areg[c] = sc;
      mx = fmaxf(mx, sc);
    }
#pragma unroll
    for (int off = 8; off; off >>= 1) mx = fmaxf(mx, __shfl_xor(mx, off, 16));
    float zs = 0.f;
#pragma unroll
    for (int c = 0; c < 4; ++c) {
      float e = __expf(areg[c] - mx);          // exp(-inf - mx) = 0 for invalid slots
      areg[c] = e;
      zs += e;
    }
#pragma unroll
    for (int off = 8; off; off >>= 1) zs += __shfl_xor(zs, off, 16);
    float zi = 1.f / (zs + 1e-16f);

#pragma unroll
    for (int c = 0; c < 4; ++c) {
      int base = s0 + c*16;
      if (base < s1) {
        int cnt = s1 - base;                  // >=1; loop caps at 16
#pragma unroll
        for (int e = 0; e < 16; ++e) {
          if (e < cnt) {
            int   ue = __shfl(ureg[c], e, 16);
            float ae = __shfl(areg[c], e, 16);
            float4 hv = *((const float4*)(h + (size_t)ue*HD) + l16);
            acc.x += ae*hv.x; acc.y += ae*hv.y; acc.z += ae*hv.z; acc.w += ae*hv.w;
          }
        }
      }
    }
    acc.x *= zi; acc.y *= zi; acc.z *= zi; acc.w *= zi;
  } else {
    float mx = -INFINITY;
    for (int i = s0 + l16; i < s1; i += 16) {
      float sc = ssrc[csr[i]] + sdv;
      sc = (sc > 0.f) ? sc : NEG*sc;
      mx = fmaxf(mx, sc);
    }
#pragma unroll
    for (int off = 8; off; off >>= 1) mx = fmaxf(mx, __shfl_xor(mx, off, 16));
    float zs = 0.f;
    for (int i = s0 + l16; i < s1; i += 16) {
      float sc = ssrc[csr[i]] + sdv;
      sc = (sc > 0.f) ? sc : NEG*sc;
      zs += __expf(sc - mx);
    }
#pragma unroll
    for (int off = 8; off; off >>= 1) zs += __shfl_xor(zs, off, 16);
    float zi = 1.f / (zs + 1e-16f);
    for (int i = s0; i < s1; ++i) {
      int u = csr[i];
      float sc = ssrc[u] + sdv;
      sc = (sc > 0.f) ? sc : NEG*sc;
      float p = __expf(sc - mx);
      float4 hv = *((const float4*)(h + (size_t)u*HD) + l16);
      acc.x += p*hv.x; acc.y += p*hv.y; acc.z += p*hv.z; acc.w += p*hv.w;
    }
    acc.x *= zi; acc.y *= zi; acc.z *= zi; acc.w *= zi;
  }
  *((float4*)(mout + (size_t)node*HD) + l16) = acc;
}

// ---------------- GRU GEMM v7: lane-per-column, M=32, B staged through LDS (k-tiled) ----------------
// Block reads B exactly ONCE from L2 (4 tiles x 32KB). B ds_read is the contiguous
// 64x16B throughput pattern (no conflicts). A reads are wave-uniform broadcasts.
// LDS 16+32 = 48KB -> 3 blocks/CU = 12 waves/CU.
__global__ void __launch_bounds__(256, 3) k_gru7(const float* __restrict__ mm, float* __restrict__ h,
                      const float* __restrict__ B, const float* __restrict__ bc,
                      const float* __restrict__ aatt, int n,
                      float* __restrict__ ssrc, float* __restrict__ sdst) {
  __shared__ float A[128][32];    // 16KB: rows 0..63 = m, rows 64..127 = h
  __shared__ float Bt[BK][256];   // 32KB tile of B
  int m_base = blockIdx.x * 32;
  int tx = threadIdx.x;
  {
    int m = tx & 31;
    int kq8 = tx >> 5;           // 0..7
    int node = m_base + m;
    bool valid = node < n;
    const float4* m4 = (const float4*)(mm + (size_t)node*HD);
    const float4* h4 = (const float4*)(h  + (size_t)node*HD);
#pragma unroll
    for (int it = 0; it < 4; ++it) {
      int kq = kq8*4 + it;       // 0..31
      int k0 = kq*4;
      float4 v = make_float4(0.f,0.f,0.f,0.f);
      if (valid) v = (kq < 16) ? m4[kq] : h4[kq - 16];
      A[k0+0][m] = v.x; A[k0+1][m] = v.y; A[k0+2][m] = v.z; A[k0+3][m] = v.w;
    }
  }

  int lane = tx & 63;            // j = lane
  int m0 = (tx >> 6) * 8;        // 8 nodes per thread

  float acc[8][4];
#pragma unroll
  for (int a = 0; a < 8; ++a)
#pragma unroll
    for (int b = 0; b < 4; ++b) acc[a][b] = 0.f;

  float4* BtV = (float4*)&Bt[0][0];

#pragma unroll
  for (int t = 0; t < 128/BK; ++t) {
    // stage B tile: 32x256 floats = 2048 float4, 8 per thread, coalesced
    const float4* gsrc = (const float4*)(B + (size_t)t*BK*256);
#pragma unroll
    for (int i = 0; i < 8; ++i) {
      int idx = tx + i*256;
      BtV[idx] = gsrc[idx];
    }
    __syncthreads();             // tile (and A, on t=0) visible

#pragma unroll 4
    for (int kk = 0; kk < BK; ++kk) {
      int k = t*BK + kk;
      float4 b  = *((const float4*)&Bt[kk][0] + lane);
      float4 a0 = *(const float4*)(&A[k][m0]);
      float4 a1 = *(const float4*)(&A[k][m0+4]);
      float av[8] = {a0.x,a0.y,a0.z,a0.w, a1.x,a1.y,a1.z,a1.w};
#pragma unroll
      for (int a = 0; a < 8; ++a) {
        acc[a][0] += av[a]*b.x;
        acc[a][1] += av[a]*b.y;
        acc[a][2] += av[a]*b.z;
        acc[a][3] += av[a]*b.w;
      }
    }
    __syncthreads();             // done reading tile before overwrite
  }

  float4 bcr = *(const float4*)(bc + 4*lane);
  float a_s = aatt[lane];
  float a_d = aatt[HD + lane];

#pragma unroll
  for (int a = 0; a < 8; ++a) {
    int node = m_base + m0 + a;
    float hold = (node < n) ? h[(size_t)node*HD + lane] : 0.f;
    float r   = acc[a][0] + bcr.x;
    float zz  = acc[a][1] + bcr.y;
    float gin = acc[a][2] + bcr.z;
    float ghn = acc[a][3] + bcr.w;
    float rg = sigmoidf_(r);
    float zg = sigmoidf_(zz);
    float ng = tanhf_(gin + rg*ghn);
    float hnew = (1.f - zg)*ng + zg*hold;
    if (node < n) h[(size_t)node*HD + lane] = hnew;
    float ps = hnew * a_s;
    float pd = hnew * a_d;
#pragma unroll
    for (int off = 32; off; off >>= 1) { ps += __shfl_xor(ps, off); pd += __shfl_xor(pd, off); }
    if (lane == 0 && node < n) { ssrc[node] = ps; sdst[node] = pd; }
  }
}

// ---------------- pooling: two-stage ----------------
__device__ __forceinline__ int lower_bound_i(const int* a, int n, int key) {
  int lo = 0, hi = n;
  while (lo < hi) { int mid = (lo + hi) >> 1; if (a[mid] < key) lo = mid + 1; else hi = mid; }
  return lo;
}

__global__ void k_pool1(const float* __restrict__ h, const int* __restrict__ batch, int n,
                        float* __restrict__ psum, float* __restrict__ pmax) {
  int g = blockIdx.x >> 3, slice = blockIdx.x & 7;
  int lane = threadIdx.x;            // 64 lanes = HD
  int lo = lower_bound_i(batch, n, g);
  int hi = lower_bound_i(batch, n, g + 1);
  int span = hi - lo;
  int s0 = lo + (int)(((long long)span * slice) >> 3);
  int s1 = lo + (int)(((long long)span * (slice + 1)) >> 3);
  float sum0 = 0.f, sum1 = 0.f, sum2 = 0.f, sum3 = 0.f;
  float mx0 = -INFINITY, mx1 = -INFINITY, mx2 = -INFINITY, mx3 = -INFINITY;
  int i = s0;
  for (; i + 3 < s1; i += 4) {
    float v0 = h[(size_t)(i+0)*HD + lane];
    float v1 = h[(size_t)(i+1)*HD + lane];
    float v2 = h[(size_t)(i+2)*HD + lane];
    float v3 = h[(size_t)(i+3)*HD + lane];
    sum0 += v0; sum1 += v1; sum2 += v2; sum3 += v3;
    mx0 = fmaxf(mx0, v0); mx1 = fmaxf(mx1, v1); mx2 = fmaxf(mx2, v2); mx3 = fmaxf(mx3, v3);
  }
  for (; i < s1; ++i) {
    float v = h[(size_t)i*HD + lane];
    sum0 += v; mx0 = fmaxf(mx0, v);
  }
  float sum = (sum0 + sum1) + (sum2 + sum3);
  float mx = fmaxf(fmaxf(mx0, mx1), fmaxf(mx2, mx3));
  psum[(size_t)blockIdx.x*HD + lane] = sum;
  pmax[(size_t)blockIdx.x*HD + lane] = mx;
}

__global__ void k_pool2(const float* __restrict__ psum, const float* __restrict__ pmax,
                        const int* __restrict__ batch, int n, float* __restrict__ gpool) {
  int g = blockIdx.x;
  int lane = threadIdx.x;
  int lo = lower_bound_i(batch, n, g);
  int hi = lower_bound_i(batch, n, g + 1);
  int cnt = hi - lo;
  float sum = 0.f, mx = -INFINITY;
#pragma unroll
  for (int s = 0; s < 8; ++s) {
    sum += psum[(size_t)(g*8+s)*HD + lane];
    mx = fmaxf(mx, pmax[(size_t)(g*8+s)*HD + lane]);
  }
  float mean = sum / fmaxf((float)cnt, 1.f);
  if (cnt <= 0 || !isfinite(mx)) mx = 0.f;
  gpool[(size_t)g*2*HD + lane] = mean;
  gpool[(size_t)g*2*HD + HD + lane] = mx;
}

// ---------------- MLP head (block per graph, one wave) ----------------
__global__ void k_head(const float* __restrict__ gpool, const float* __restrict__ W1,
                       const float* __restrict__ b1, const float* __restrict__ W2,
                       const float* __restrict__ b2, float* __restrict__ out) {
  int g = blockIdx.x, j = threadIdx.x;
  const float* gr = gpool + (size_t)g*2*HD;
  float acc = b1[j];
#pragma unroll
  for (int k = 0; k < 2*HD; ++k) acc += gr[k] * W1[k*HD + j];
  acc = fmaxf(acc, 0.f);
  float v = acc * W2[j];
#pragma unroll
  for (int off = 32; off; off >>= 1) v += __shfl_xor(v, off);
  if (j == 0) out[g] = v + b2[0];
}

extern "C" void kernel_launch(void* const* d_in, const int* in_sizes, int n_in,
                              void* d_out, int out_size, void* d_ws, size_t ws_size,
                              hipStream_t stream) {
  const float* x     = (const float*)d_in[0];
  const int*   ei    = (const int*)d_in[1];
  const int*   batch = (const int*)d_in[2];
  const float* Win   = (const float*)d_in[3];
  const float* bin   = (const float*)d_in[4];
  const float* aatt  = (const float*)d_in[5];
  const float* Wi    = (const float*)d_in[6];
  const float* Wh    = (const float*)d_in[7];
  const float* bi    = (const float*)d_in[8];
  const float* bh    = (const float*)d_in[9];
  const float* W1    = (const float*)d_in[10];
  const float* b1    = (const float*)d_in[11];
  const float* W2    = (const float*)d_in[12];
  const float* b2    = (const float*)d_in[13];
  float* out = (float*)d_out;

  int N = in_sizes[0] / DIN;
  int E = in_sizes[1] / 2;
  int G = out_size;

  const int* srcp = ei;
  const int* dstp = ei + E;

  char* base = (char*)d_ws;
  size_t off = 0;
  auto alloc = [&](size_t bytes) -> char* {
    char* p = base + off;
    off += (bytes + 255) & ~(size_t)255;
    return p;
  };
  float* h     = (float*)alloc((size_t)N*HD*4);
  float* mbuf  = (float*)alloc((size_t)N*HD*4);
  float* ssrc  = (float*)alloc((size_t)N*4);
  float* sdst  = (float*)alloc((size_t)N*4);
  int*   deg   = (int*)  alloc((size_t)N*4);
  int*   rowst = (int*)  alloc((size_t)(N+1)*4);
  int*   csr   = (int*)  alloc((size_t)E*4);
  float* B     = (float*)alloc((size_t)128*256*4);
  float* bc    = (float*)alloc((size_t)256*4);
  float* gpool = (float*)alloc((size_t)G*2*HD*4);
  float* psum  = (float*)alloc((size_t)G*8*HD*4);
  float* pmax  = (float*)alloc((size_t)G*8*HD*4);
  int*   bsum  = (int*)  alloc(1024);
  (void)ws_size; (void)n_in;

  int nbN = (N + 255)/256, nbE = (E + 255)/256;

  hipMemsetAsync(deg, 0, (size_t)N*4, stream);
  k_count<<<nbE, 256, 0, stream>>>(dstp, E, deg);
  k_scan1<<<nbN, 256, 0, stream>>>(deg, N, rowst, bsum);
  k_scan2<<<1, 256, 0, stream>>>(bsum, nbN);
  k_scan3<<<nbN, 256, 0, stream>>>(rowst, bsum, N, E, deg);
  k_scatter<<<nbE, 256, 0, stream>>>(srcp, dstp, E, rowst, deg, csr);
  k_wt2<<<(128*256 + 255)/256, 256, 0, stream>>>(Wi, Wh, bi, bh, B, bc);
  k_proj2<<<(N + 31)/32, 256, 0, stream>>>(x, Win, bin, aatt, N, h, ssrc, sdst);
  for (int t = 0; t < 3; ++t) {
    k_sagg<<<(N + 15)/16, 256, 0, stream>>>(h, ssrc, sdst, rowst, csr, N, mbuf);
    k_gru7<<<(N + 31)/32, 256, 0, stream>>>(mbuf, h, B, bc, aatt, N, ssrc, sdst);
  }
  k_pool1<<<G*8, 64, 0, stream>>>(h, batch, N, psum, pmax);
  k_pool2<<<G, 64, 0, stream>>>(psum, pmax, batch, N, gpool);
  k_head<<<G, 64, 0, stream>>>(gpool, W1, b1, W2, b2, out);
}